// Round 5
// baseline (481.984 us; speedup 1.0000x reference)
//
#include <hip/hip_runtime.h>
#include <hip/hip_bf16.h>

#define E_ 8
#define H_ 1024
#define I_ 4096
#define T_ 4096
#define CAP_ 1024

typedef __attribute__((ext_vector_type(8))) short bf16x8;
typedef __attribute__((ext_vector_type(4))) float f32x4;

// fp32 -> bf16 round-to-nearest-even
__device__ __forceinline__ unsigned short f2bf(float f) {
  union { float f; unsigned int u; } v; v.f = f;
  unsigned int r = v.u + 0x7FFFu + ((v.u >> 16) & 1u);
  return (unsigned short)(r >> 16);
}

// async global->LDS, 16B per lane; lds dest = wave-uniform base + lane*16
__device__ __forceinline__ void gload16(const void* g, void* l) {
  __builtin_amdgcn_global_load_lds(
      (const __attribute__((address_space(1))) unsigned int*)g,
      (__attribute__((address_space(3))) unsigned int*)l, 16, 0, 0);
}

// ---------------- x fp32 -> bf16 (device body; grid-stride) ----------------
__device__ __forceinline__ void cvt_body(const float* __restrict__ in,
                                         unsigned short* __restrict__ out,
                                         int n4, int bid, int nblocks) {
  int i = bid * 256 + threadIdx.x;
  const int stride = nblocks * 256;
  for (; i < n4; i += stride) {
    float4 v = ((const float4*)in)[i];
    ushort4 o;
    o.x = f2bf(v.x); o.y = f2bf(v.y); o.z = f2bf(v.z); o.w = f2bf(v.w);
    ((ushort4*)out)[i] = o;
  }
}

// ------- out init (ATOMIC fallback path): out[t][c] = b2[eid(t)][c] -------
__global__ void init_out(float* __restrict__ out, const float* __restrict__ b2,
                         const int* __restrict__ loads) {
  const int idx = blockIdx.x * blockDim.x + threadIdx.x;  // one float4 each
  if (idx >= T_ * H_ / 4) return;
  const int row = idx >> 8;            // H/4 = 256 float4 per row
  const int c4 = (idx & 255) * 4;
  int acc = 0, e = 0;
#pragma unroll
  for (int i = 0; i < E_; ++i) {
    int li = loads[i];
    if (row >= acc + li) e = i + 1;
    acc += li;
  }
  float4 b = *(const float4*)&b2[(size_t)e * H_ + c4];
  ((float4*)out)[idx] = b;
}

// ------- out = b2[eid] + sum_ks partials[ks]  (partials path) -------
__global__ void reduce_out(const float* __restrict__ partials,
                           const float* __restrict__ b2,
                           const int* __restrict__ loads,
                           float* __restrict__ out) {
  const int idx = blockIdx.x * blockDim.x + threadIdx.x;  // one float4 each
  if (idx >= T_ * H_ / 4) return;
  const int row = idx >> 8;
  const int c4 = (idx & 255) * 4;
  int acc = 0, e = 0;
#pragma unroll
  for (int i = 0; i < E_; ++i) {
    int li = loads[i];
    if (row >= acc + li) e = i + 1;
    acc += li;
  }
  float4 s = *(const float4*)&b2[(size_t)e * H_ + c4];
  constexpr size_t STRIDE4 = (size_t)T_ * H_ / 4;
#pragma unroll
  for (int ks = 0; ks < 4; ++ks) {
    float4 p = ((const float4*)partials)[ks * STRIDE4 + idx];
    s.x += p.x; s.y += p.y; s.z += p.z; s.w += p.w;
  }
  ((float4*)out)[idx] = s;
}

// ------------- one 64x64 transpose+cvt tile: A[R][C] fp32 -> B[C][R] bf16 ----
// (A, B already offset to the expert's matrix base)
__device__ __forceinline__ void transpose_tile(const float* __restrict__ A,
                                               unsigned short* __restrict__ B,
                                               int R, int C, int r0, int c0) {
  __shared__ float tile[64][65];  // +1 pad: LDS reads land 2-way max (free)
  const int t = threadIdx.x;
#pragma unroll
  for (int p = 0; p < 4; ++p) {
    int r = (t >> 4) + p * 16;
    int c = (t & 15) * 4;
    float4 v = *(const float4*)&A[(size_t)(r0 + r) * C + (c0 + c)];
    tile[r][c + 0] = v.x; tile[r][c + 1] = v.y;
    tile[r][c + 2] = v.z; tile[r][c + 3] = v.w;
  }
  __syncthreads();
#pragma unroll
  for (int p = 0; p < 4; ++p) {
    int c  = (t >> 4) + p * 16;  // out row (original column)
    int rr = (t & 15) * 4;       // out col base (original row)
    ushort4 o;
    o.x = f2bf(tile[rr + 0][c]);
    o.y = f2bf(tile[rr + 1][c]);
    o.z = f2bf(tile[rr + 2][c]);
    o.w = f2bf(tile[rr + 3][c]);
    *(ushort4*)&B[(size_t)(c0 + c) * R + (r0 + rr)] = o;
  }
}

// ------- fused: x fp32->bf16 (512 blocks) + W1 [E][H][I] -> [E][I][H] -------
// cvt blocks touch no LDS; branch is block-uniform; no data dependence.
__global__ __launch_bounds__(256) void fused_cvt_t1(
    const float* __restrict__ x, unsigned short* __restrict__ x_bf,
    const float* __restrict__ W1, unsigned short* __restrict__ w1t) {
  const int bid = blockIdx.x;  // 0..8703
  if (bid < 512) {
    cvt_body(x, x_bf, (T_ * H_) / 4, bid, 512);
  } else {
    const int tt = bid - 512;            // 0..8191: E * (I/64=64 c-tiles) * (H/64=16 r-tiles)
    const int e = tt >> 10, rem = tt & 1023;
    // W1 is [H][I]: R=H rows, C=I cols; output w1t is [I][H]
    transpose_tile(W1 + (size_t)e * H_ * I_, w1t + (size_t)e * H_ * I_,
                   H_, I_, (rem & 15) * 64, (rem >> 4) * 64);
  }
}

// ------------- grouped GEMM tile: C[m,n] = A[m,:] @ BT[n,:]^T -------------
// A: bf16 [T][K] (row = global token index, experts contiguous)
// BT: bf16 [E][N][K] (pre-transposed weight)
// EPI 0: bf16 store of gelu(acc + bias)      (GEMM1 -> hbuf)
// EPI 1: fp32 store of acc to partials[ks]   (GEMM2, partials path)
// EPI 2: fp32 unsafeAtomicAdd of acc to out  (GEMM2, atomic fallback)
template <int K, int N, int KSPLIT, int EPI>
__device__ __forceinline__ void gemm_tile(
    const unsigned short* __restrict__ Abase,
    const unsigned short* __restrict__ BT,
    const float* __restrict__ bias,
    const int* __restrict__ loads,
    void* __restrict__ out_ptr,
    int e, int mtile, int ntile, int ks) {
  __shared__ unsigned short lds_a[128 * 32];
  __shared__ unsigned short lds_b[128 * 32];
  constexpr int KCH = K / KSPLIT;  // K range per block (multiple of 32)

  int seg0 = 0, load_e = 0;
#pragma unroll
  for (int i = 0; i < E_; ++i) {
    int li = loads[i];
    seg0 += (i < e) ? li : 0;
    if (i == e) load_e = li;
  }
  const int row0 = mtile * 128;
  if (row0 >= load_e) return;  // empty tile: whole block exits uniformly
  const int ncol0 = ntile * 128;

  const int t = threadIdx.x;
  const int lane = t & 63;
  const int w = t >> 6;
  const int wr = w >> 1, wc = w & 1;

  const unsigned short* Bexp = BT + (size_t)e * N * K;

  f32x4 acc[4][4];
#pragma unroll
  for (int i = 0; i < 4; ++i)
#pragma unroll
    for (int j = 0; j < 4; ++j) acc[i][j] = (f32x4){0.f, 0.f, 0.f, 0.f};

  // staging: chunk c = it*256 + t -> tile row c>>2, elem off (c&3)*8;
  // LDS linear [128][32] shorts, dest = wave-uniform base + lane*16B,
  // so short-offset c*8 == (c>>2)*32 + (c&3)*8 (identity, audited).
  const unsigned short* gA[2];
  const unsigned short* gB[2];
  unsigned short* ldsA[2];
  unsigned short* ldsB[2];
#pragma unroll
  for (int it = 0; it < 2; ++it) {
    int c = it * 256 + t;
    int rowi = c >> 2, off = (c & 3) * 8;
    int gr = seg0 + row0 + rowi;
    if (gr > T_ - 1) gr = T_ - 1;  // clamp (values masked at store)
    gA[it] = Abase + (size_t)gr * K + ks * KCH + off;
    gB[it] = Bexp + (size_t)(ncol0 + rowi) * K + ks * KCH + off;
    ldsA[it] = &lds_a[(size_t)(it * 256 + w * 64) * 8];
    ldsB[it] = &lds_b[(size_t)(it * 256 + w * 64) * 8];
  }

  const int r = lane & 15, kq = lane >> 4;

  for (int kt = 0; kt < KCH / 32; ++kt) {
    const int kb = kt * 32;
#pragma unroll
    for (int it = 0; it < 2; ++it) {
      gload16(gA[it] + kb, ldsA[it]);
      gload16(gB[it] + kb, ldsB[it]);
    }
    __syncthreads();  // drains vmcnt -> LDS tiles ready
    bf16x8 av[4], bv[4];
#pragma unroll
    for (int mi = 0; mi < 4; ++mi)
      av[mi] = *(const bf16x8*)&lds_a[(wr * 64 + mi * 16 + r) * 32 + kq * 8];
#pragma unroll
    for (int ni = 0; ni < 4; ++ni)
      bv[ni] = *(const bf16x8*)&lds_b[(wc * 64 + ni * 16 + r) * 32 + kq * 8];
#pragma unroll
    for (int mi = 0; mi < 4; ++mi)
#pragma unroll
      for (int ni = 0; ni < 4; ++ni)
        acc[mi][ni] = __builtin_amdgcn_mfma_f32_16x16x32_bf16(
            av[mi], bv[ni], acc[mi][ni], 0, 0, 0);
    __syncthreads();  // all reads done before next stage overwrites
  }

  // epilogue: D[row=(lane>>4)*4+reg][col=lane&15] per 16x16 fragment
  const int r4 = (lane >> 4) * 4;
  const int cc = lane & 15;
  const bool full_tile = (row0 + 128 <= load_e);  // wave-uniform for interior
  float* outf = (float*)out_ptr;
  if constexpr (EPI == 1) outf += (size_t)ks * T_ * N;
#pragma unroll
  for (int ni = 0; ni < 4; ++ni) {
    const int col = ncol0 + wc * 64 + ni * 16 + cc;
    float bv = 0.f;
    if constexpr (EPI == 0) bv = bias[(size_t)e * N + col];
#pragma unroll
    for (int mi = 0; mi < 4; ++mi) {
#pragma unroll
      for (int rr = 0; rr < 4; ++rr) {
        const int rowl = row0 + wr * 64 + mi * 16 + r4 + rr;
        if (full_tile || rowl < load_e) {
          float v = acc[mi][ni][rr] + bv;
          const size_t o = (size_t)(seg0 + rowl) * N + col;
          if constexpr (EPI == 0) {
            v = 0.5f * v * (1.0f + erff(v * 0.70710678118f));
            ((unsigned short*)out_ptr)[o] = f2bf(v);
          } else if constexpr (EPI == 1) {
            outf[o] = v;
          } else {
            unsafeAtomicAdd(&outf[o], v);
          }
        }
      }
    }
  }
}

// standalone grouped GEMM; blockIdx.z = e*KSPLIT + ks
template <int K, int N, int KSPLIT, int EPI>
__global__ __launch_bounds__(256) void grouped_gemm(
    const unsigned short* __restrict__ Abase,
    const unsigned short* __restrict__ BT,
    const float* __restrict__ bias,
    const int* __restrict__ loads,
    void* __restrict__ out_ptr) {
  gemm_tile<K, N, KSPLIT, EPI>(Abase, BT, bias, loads, out_ptr,
                               (int)blockIdx.z / KSPLIT, (int)blockIdx.y,
                               (int)blockIdx.x, (int)blockIdx.z % KSPLIT);
}

// ------------- fused dispatch: GEMM1 blocks + transpose-W2 blocks -----------
// No data dependence (GEMM1 reads x_bf/w1t, transpose reads W2). 4:1
// interleave (8192 transpose : 2048 gemm) so every CU co-schedules BW-bound
// transpose waves with MFMA-bound gemm waves (m114 mechanism), and transpose
// blocks backfill GEMM1's tail.
__global__ __launch_bounds__(256) void fused_g1_t2(
    const unsigned short* __restrict__ x_bf,
    const unsigned short* __restrict__ w1t,
    const float* __restrict__ b1,
    const int* __restrict__ loads,
    unsigned short* __restrict__ hbuf,
    const float* __restrict__ W2,
    unsigned short* __restrict__ w2t) {
  const int bid = blockIdx.x;  // 0..10239
  const int sel = bid % 5;
  if (sel == 4) {
    const int g = bid / 5;             // 0..2047 gemm tile
    const int e = g >> 8, rem = g & 255;
    gemm_tile<H_, I_, 1, 0>(x_bf, w1t, b1, loads, (void*)hbuf,
                            e, rem >> 5, rem & 31, 0);
  } else {
    const int tt = (bid / 5) * 4 + sel;  // 0..8191 transpose tile
    const int e = tt >> 10, rem = tt & 1023;
    // W2 is [I][H]: R=I, C=H; output w2t is [H][I]
    transpose_tile(W2 + (size_t)e * I_ * H_, w2t + (size_t)e * I_ * H_,
                   I_, H_, (rem >> 4) * 64, (rem & 15) * 64);
  }
}

extern "C" void kernel_launch(void* const* d_in, const int* in_sizes, int n_in,
                              void* d_out, int out_size, void* d_ws,
                              size_t ws_size, hipStream_t stream) {
  const float* x = (const float*)d_in[0];
  const int* loads = (const int*)d_in[1];
  const float* W1 = (const float*)d_in[2];
  const float* b1 = (const float*)d_in[3];
  const float* W2 = (const float*)d_in[4];
  const float* b2 = (const float*)d_in[5];
  float* out = (float*)d_out;

  char* ws = (char*)d_ws;
  unsigned short* x_bf = (unsigned short*)(ws);                             // 8 MiB
  unsigned short* w1t  = (unsigned short*)(ws + ((size_t)8 << 20));         // 64 MiB
  unsigned short* w2t  = (unsigned short*)(ws + ((size_t)72 << 20));        // 64 MiB
  unsigned short* hbuf = (unsigned short*)(ws + ((size_t)136 << 20));       // 32 MiB
  float* partials      = (float*)(ws + ((size_t)168 << 20));                // 64 MiB
  // partials path needs 232 MiB of ws; ws_size is launch-constant, so the
  // same branch is taken every call (graph-capture safe).
  const bool use_partials = ws_size >= ((size_t)232 << 20);

  if (!use_partials)  // atomic fallback needs out pre-filled with bias
    init_out<<<(T_ * H_ / 4 + 255) / 256, 256, 0, stream>>>(out, b2, loads);
  // x fp32->bf16  ||  w1t = W1^T bf16
  fused_cvt_t1<<<8704, 256, 0, stream>>>(x, x_bf, W1, w1t);
  // hbuf = gelu(x @ W1 + b1) bf16  ||  w2t = W2^T bf16
  fused_g1_t2<<<10240, 256, 0, stream>>>(x_bf, w1t, b1, loads, hbuf, W2, w2t);
  if (use_partials) {
    // partials[ks] = h @ W2 (K-chunk ks); then out = b2[eid] + sum partials
    grouped_gemm<I_, H_, 4, 1>
        <<<dim3(H_ / 128, CAP_ / 128, E_ * 4), 256, 0, stream>>>(
            hbuf, w2t, nullptr, loads, (void*)partials);
    reduce_out<<<(T_ * H_ / 4 + 255) / 256, 256, 0, stream>>>(partials, b2,
                                                              loads, out);
  } else {
    // out += h @ W2 via fp32 atomics (bias already in out)
    grouped_gemm<I_, H_, 4, 2>
        <<<dim3(H_ / 128, CAP_ / 128, E_ * 4), 256, 0, stream>>>(
            hbuf, w2t, nullptr, loads, out);
  }
}

// Round 8
// 480.690 us; speedup vs baseline: 1.0027x; 1.0027x over previous
//
#include <hip/hip_runtime.h>
#include <hip/hip_bf16.h>

#define E_ 8
#define H_ 1024
#define I_ 4096
#define T_ 4096
#define CAP_ 1024

// LDS union: max(transpose 64*65*4 = 16640 B, gemm 2*8192 = 16384 B)
#define SMEM_BYTES 16640

typedef __attribute__((ext_vector_type(8))) short bf16x8;
typedef __attribute__((ext_vector_type(4))) float f32x4;

// fp32 -> bf16 round-to-nearest-even
__device__ __forceinline__ unsigned short f2bf(float f) {
  union { float f; unsigned int u; } v; v.f = f;
  unsigned int r = v.u + 0x7FFFu + ((v.u >> 16) & 1u);
  return (unsigned short)(r >> 16);
}

// async global->LDS, 16B per lane; lds dest = wave-uniform base + lane*16
__device__ __forceinline__ void gload16(const void* g, void* l) {
  __builtin_amdgcn_global_load_lds(
      (const __attribute__((address_space(1))) unsigned int*)g,
      (__attribute__((address_space(3))) unsigned int*)l, 16, 0, 0);
}

// ---------------- x fp32 -> bf16 (device body; grid-stride) ----------------
__device__ __forceinline__ void cvt_body(const float* __restrict__ in,
                                         unsigned short* __restrict__ out,
                                         int n4, int bid, int nblocks) {
  int i = bid * 256 + threadIdx.x;
  const int stride = nblocks * 256;
  for (; i < n4; i += stride) {
    float4 v = ((const float4*)in)[i];
    ushort4 o;
    o.x = f2bf(v.x); o.y = f2bf(v.y); o.z = f2bf(v.z); o.w = f2bf(v.w);
    ((ushort4*)out)[i] = o;
  }
}

// ------- out init (ATOMIC fallback path): out[t][c] = b2[eid(t)][c] -------
__global__ void init_out(float* __restrict__ out, const float* __restrict__ b2,
                         const int* __restrict__ loads) {
  const int idx = blockIdx.x * blockDim.x + threadIdx.x;  // one float4 each
  if (idx >= T_ * H_ / 4) return;
  const int row = idx >> 8;            // H/4 = 256 float4 per row
  const int c4 = (idx & 255) * 4;
  int acc = 0, e = 0;
#pragma unroll
  for (int i = 0; i < E_; ++i) {
    int li = loads[i];
    if (row >= acc + li) e = i + 1;
    acc += li;
  }
  float4 b = *(const float4*)&b2[(size_t)e * H_ + c4];
  ((float4*)out)[idx] = b;
}

// ------- out = b2[eid] + sum_ks partials[ks]  (partials path) -------
__global__ void reduce_out(const float* __restrict__ partials,
                           const float* __restrict__ b2,
                           const int* __restrict__ loads,
                           float* __restrict__ out) {
  const int idx = blockIdx.x * blockDim.x + threadIdx.x;  // one float4 each
  if (idx >= T_ * H_ / 4) return;
  const int row = idx >> 8;
  const int c4 = (idx & 255) * 4;
  int acc = 0, e = 0;
#pragma unroll
  for (int i = 0; i < E_; ++i) {
    int li = loads[i];
    if (row >= acc + li) e = i + 1;
    acc += li;
  }
  float4 s = *(const float4*)&b2[(size_t)e * H_ + c4];
  constexpr size_t STRIDE4 = (size_t)T_ * H_ / 4;
#pragma unroll
  for (int ks = 0; ks < 4; ++ks) {
    float4 p = ((const float4*)partials)[ks * STRIDE4 + idx];
    s.x += p.x; s.y += p.y; s.z += p.z; s.w += p.w;
  }
  ((float4*)out)[idx] = s;
}

// ------------- one 64x64 transpose+cvt tile: A[R][C] fp32 -> B[C][R] bf16 ----
// (A, B already offset to the expert's matrix base; smem >= 16640 B)
__device__ __forceinline__ void transpose_tile(const float* __restrict__ A,
                                               unsigned short* __restrict__ B,
                                               int R, int C, int r0, int c0,
                                               char* smem) {
  float (*tile)[65] = (float(*)[65])smem;  // [64][65]; +1 pad: reads 2-way max
  const int t = threadIdx.x;
#pragma unroll
  for (int p = 0; p < 4; ++p) {
    int r = (t >> 4) + p * 16;
    int c = (t & 15) * 4;
    float4 v = *(const float4*)&A[(size_t)(r0 + r) * C + (c0 + c)];
    tile[r][c + 0] = v.x; tile[r][c + 1] = v.y;
    tile[r][c + 2] = v.z; tile[r][c + 3] = v.w;
  }
  __syncthreads();
#pragma unroll
  for (int p = 0; p < 4; ++p) {
    int c  = (t >> 4) + p * 16;  // out row (original column)
    int rr = (t & 15) * 4;       // out col base (original row)
    ushort4 o;
    o.x = f2bf(tile[rr + 0][c]);
    o.y = f2bf(tile[rr + 1][c]);
    o.z = f2bf(tile[rr + 2][c]);
    o.w = f2bf(tile[rr + 3][c]);
    *(ushort4*)&B[(size_t)(c0 + c) * R + (r0 + rr)] = o;
  }
}

// ------- fused: x fp32->bf16 (512 blocks) + W1 [E][H][I] -> [E][I][H] -------
// cvt blocks touch no LDS; branch is block-uniform; no data dependence.
__global__ __launch_bounds__(256) void fused_cvt_t1(
    const float* __restrict__ x, unsigned short* __restrict__ x_bf,
    const float* __restrict__ W1, unsigned short* __restrict__ w1t) {
  __shared__ __align__(16) char smem[SMEM_BYTES];
  const int bid = blockIdx.x;  // 0..8703
  if (bid < 512) {
    cvt_body(x, x_bf, (T_ * H_) / 4, bid, 512);
  } else {
    const int tt = bid - 512;  // 0..8191: E * (I/64=64 c-tiles) * (H/64=16 r-tiles)
    const int e = tt >> 10, rem = tt & 1023;
    // W1 is [H][I]: R=H rows, C=I cols; output w1t is [I][H]
    transpose_tile(W1 + (size_t)e * H_ * I_, w1t + (size_t)e * H_ * I_,
                   H_, I_, (rem & 15) * 64, (rem >> 4) * 64, smem);
  }
}

// ------------- grouped GEMM tile: C[m,n] = A[m,:] @ BT[n,:]^T -------------
// A: bf16 [T][K] (row = global token index, experts contiguous)
// BT: bf16 [E][N][K] (pre-transposed weight)
// EPI 0: bf16 store of gelu(acc + bias)      (GEMM1 -> hbuf)
// EPI 1: fp32 store of acc to partials[ks]   (GEMM2, partials path)
// EPI 2: fp32 unsafeAtomicAdd of acc to out  (GEMM2, atomic fallback)
// SETPRIO: wrap MFMA cluster in s_setprio (only useful with wave role
// diversity on the CU, i.e. the fused heterogeneous dispatch — T5 regime).
template <int K, int N, int KSPLIT, int EPI, bool SETPRIO>
__device__ __forceinline__ void gemm_tile(
    const unsigned short* __restrict__ Abase,
    const unsigned short* __restrict__ BT,
    const float* __restrict__ bias,
    const int* __restrict__ loads,
    void* __restrict__ out_ptr,
    int e, int mtile, int ntile, int ks, char* smem) {
  unsigned short* lds_a = (unsigned short*)smem;            // [128][32]
  unsigned short* lds_b = (unsigned short*)(smem + 8192);   // [128][32]
  constexpr int KCH = K / KSPLIT;  // K range per block (multiple of 32)

  int seg0 = 0, load_e = 0;
#pragma unroll
  for (int i = 0; i < E_; ++i) {
    int li = loads[i];
    seg0 += (i < e) ? li : 0;
    if (i == e) load_e = li;
  }
  const int row0 = mtile * 128;
  if (row0 >= load_e) return;  // empty tile: whole block exits uniformly
  const int ncol0 = ntile * 128;

  const int t = threadIdx.x;
  const int lane = t & 63;
  const int w = t >> 6;
  const int wr = w >> 1, wc = w & 1;

  const unsigned short* Bexp = BT + (size_t)e * N * K;

  f32x4 acc[4][4];
#pragma unroll
  for (int i = 0; i < 4; ++i)
#pragma unroll
    for (int j = 0; j < 4; ++j) acc[i][j] = (f32x4){0.f, 0.f, 0.f, 0.f};

  // staging: chunk c = it*256 + t -> tile row c>>2, elem off (c&3)*8;
  // LDS linear [128][32] shorts, dest = wave-uniform base + lane*16B,
  // so short-offset c*8 == (c>>2)*32 + (c&3)*8 (identity, audited).
  const unsigned short* gA[2];
  const unsigned short* gB[2];
  unsigned short* ldsA[2];
  unsigned short* ldsB[2];
#pragma unroll
  for (int it = 0; it < 2; ++it) {
    int c = it * 256 + t;
    int rowi = c >> 2, off = (c & 3) * 8;
    int gr = seg0 + row0 + rowi;
    if (gr > T_ - 1) gr = T_ - 1;  // clamp (values masked at store)
    gA[it] = Abase + (size_t)gr * K + ks * KCH + off;
    gB[it] = Bexp + (size_t)(ncol0 + rowi) * K + ks * KCH + off;
    ldsA[it] = &lds_a[(size_t)(it * 256 + w * 64) * 8];
    ldsB[it] = &lds_b[(size_t)(it * 256 + w * 64) * 8];
  }

  const int r = lane & 15, kq = lane >> 4;

  for (int kt = 0; kt < KCH / 32; ++kt) {
    const int kb = kt * 32;
#pragma unroll
    for (int it = 0; it < 2; ++it) {
      gload16(gA[it] + kb, ldsA[it]);
      gload16(gB[it] + kb, ldsB[it]);
    }
    __syncthreads();  // drains vmcnt -> LDS tiles ready
    bf16x8 av[4], bv[4];
#pragma unroll
    for (int mi = 0; mi < 4; ++mi)
      av[mi] = *(const bf16x8*)&lds_a[(wr * 64 + mi * 16 + r) * 32 + kq * 8];
#pragma unroll
    for (int ni = 0; ni < 4; ++ni)
      bv[ni] = *(const bf16x8*)&lds_b[(wc * 64 + ni * 16 + r) * 32 + kq * 8];
    if constexpr (SETPRIO) __builtin_amdgcn_s_setprio(1);
#pragma unroll
    for (int mi = 0; mi < 4; ++mi)
#pragma unroll
      for (int ni = 0; ni < 4; ++ni)
        acc[mi][ni] = __builtin_amdgcn_mfma_f32_16x16x32_bf16(
            av[mi], bv[ni], acc[mi][ni], 0, 0, 0);
    if constexpr (SETPRIO) __builtin_amdgcn_s_setprio(0);
    __syncthreads();  // all reads done before next stage overwrites
  }

  // epilogue: D[row=(lane>>4)*4+reg][col=lane&15] per 16x16 fragment
  const int r4 = (lane >> 4) * 4;
  const int cc = lane & 15;
  const bool full_tile = (row0 + 128 <= load_e);  // wave-uniform for interior
  float* outf = (float*)out_ptr;
  if constexpr (EPI == 1) outf += (size_t)ks * T_ * N;
#pragma unroll
  for (int ni = 0; ni < 4; ++ni) {
    const int col = ncol0 + wc * 64 + ni * 16 + cc;
    float bv = 0.f;
    if constexpr (EPI == 0) bv = bias[(size_t)e * N + col];
#pragma unroll
    for (int mi = 0; mi < 4; ++mi) {
#pragma unroll
      for (int rr = 0; rr < 4; ++rr) {
        const int rowl = row0 + wr * 64 + mi * 16 + r4 + rr;
        if (full_tile || rowl < load_e) {
          float v = acc[mi][ni][rr] + bv;
          const size_t o = (size_t)(seg0 + rowl) * N + col;
          if constexpr (EPI == 0) {
            v = 0.5f * v * (1.0f + erff(v * 0.70710678118f));
            ((unsigned short*)out_ptr)[o] = f2bf(v);
          } else if constexpr (EPI == 1) {
            outf[o] = v;
          } else {
            unsafeAtomicAdd(&outf[o], v);
          }
        }
      }
    }
  }
}

// standalone grouped GEMM; blockIdx.z = e*KSPLIT + ks
template <int K, int N, int KSPLIT, int EPI>
__global__ __launch_bounds__(256) void grouped_gemm(
    const unsigned short* __restrict__ Abase,
    const unsigned short* __restrict__ BT,
    const float* __restrict__ bias,
    const int* __restrict__ loads,
    void* __restrict__ out_ptr) {
  __shared__ __align__(16) char smem[16384];
  gemm_tile<K, N, KSPLIT, EPI, false>(
      Abase, BT, bias, loads, out_ptr, (int)blockIdx.z / KSPLIT,
      (int)blockIdx.y, (int)blockIdx.x, (int)blockIdx.z % KSPLIT, smem);
}

// ------------- fused dispatch: GEMM1 blocks + transpose-W2 blocks -----------
// No data dependence (GEMM1 reads x_bf/w1t, transpose reads W2). 4:1
// interleave (8192 transpose : 2048 gemm) so every CU co-schedules BW-bound
// transpose waves with MFMA-bound gemm waves (m114 mechanism). LDS is a
// UNION (16640 B) so occupancy is VGPR-limited (~6 blocks/CU), not LDS.
__global__ __launch_bounds__(256) void fused_g1_t2(
    const unsigned short* __restrict__ x_bf,
    const unsigned short* __restrict__ w1t,
    const float* __restrict__ b1,
    const int* __restrict__ loads,
    unsigned short* __restrict__ hbuf,
    const float* __restrict__ W2,
    unsigned short* __restrict__ w2t) {
  __shared__ __align__(16) char smem[SMEM_BYTES];
  const int bid = blockIdx.x;  // 0..10239
  const int sel = bid % 5;
  if (sel == 4) {
    const int g = bid / 5;             // 0..2047 gemm tile
    const int e = g >> 8, rem = g & 255;
    gemm_tile<H_, I_, 1, 0, true>(x_bf, w1t, b1, loads, (void*)hbuf,
                                  e, rem >> 5, rem & 31, 0, smem);
  } else {
    const int tt = (bid / 5) * 4 + sel;  // 0..8191 transpose tile
    const int e = tt >> 10, rem = tt & 1023;
    // W2 is [I][H]: R=I, C=H; output w2t is [H][I]
    transpose_tile(W2 + (size_t)e * I_ * H_, w2t + (size_t)e * I_ * H_,
                   I_, H_, (rem >> 4) * 64, (rem & 15) * 64, smem);
  }
}

extern "C" void kernel_launch(void* const* d_in, const int* in_sizes, int n_in,
                              void* d_out, int out_size, void* d_ws,
                              size_t ws_size, hipStream_t stream) {
  const float* x = (const float*)d_in[0];
  const int* loads = (const int*)d_in[1];
  const float* W1 = (const float*)d_in[2];
  const float* b1 = (const float*)d_in[3];
  const float* W2 = (const float*)d_in[4];
  const float* b2 = (const float*)d_in[5];
  float* out = (float*)d_out;

  char* ws = (char*)d_ws;
  unsigned short* x_bf = (unsigned short*)(ws);                             // 8 MiB
  unsigned short* w1t  = (unsigned short*)(ws + ((size_t)8 << 20));         // 64 MiB
  unsigned short* w2t  = (unsigned short*)(ws + ((size_t)72 << 20));        // 64 MiB
  unsigned short* hbuf = (unsigned short*)(ws + ((size_t)136 << 20));       // 32 MiB
  float* partials      = (float*)(ws + ((size_t)168 << 20));                // 64 MiB
  // partials path needs 232 MiB of ws; ws_size is launch-constant, so the
  // same branch is taken every call (graph-capture safe).
  const bool use_partials = ws_size >= ((size_t)232 << 20);

  if (!use_partials)  // atomic fallback needs out pre-filled with bias
    init_out<<<(T_ * H_ / 4 + 255) / 256, 256, 0, stream>>>(out, b2, loads);
  // x fp32->bf16  ||  w1t = W1^T bf16
  fused_cvt_t1<<<8704, 256, 0, stream>>>(x, x_bf, W1, w1t);
  // hbuf = gelu(x @ W1 + b1) bf16  ||  w2t = W2^T bf16
  fused_g1_t2<<<10240, 256, 0, stream>>>(x_bf, w1t, b1, loads, hbuf, W2, w2t);
  if (use_partials) {
    // partials[ks] = h @ W2 (K-chunk ks); then out = b2[eid] + sum partials
    grouped_gemm<I_, H_, 4, 1>
        <<<dim3(H_ / 128, CAP_ / 128, E_ * 4), 256, 0, stream>>>(
            hbuf, w2t, nullptr, loads, (void*)partials);
    reduce_out<<<(T_ * H_ / 4 + 255) / 256, 256, 0, stream>>>(partials, b2,
                                                              loads, out);
  } else {
    // out += h @ W2 via fp32 atomics (bias already in out)
    grouped_gemm<I_, H_, 4, 2>
        <<<dim3(H_ / 128, CAP_ / 128, E_ * 4), 256, 0, stream>>>(
            hbuf, w2t, nullptr, loads, out);
  }
}